// Round 2
// baseline (212.189 us; speedup 1.0000x reference)
//
#include <hip/hip_runtime.h>
#include <hip/hip_bf16.h>

// Problem constants: B=2, N=2048, C=1024, H=16, D=64  (head_dim)
// M = B*N = 4096 rows. qkv layout along 3C axis: three*1024 + h*64 + d.

typedef __bf16 bf16x8 __attribute__((ext_vector_type(8)));
typedef float f32x4 __attribute__((ext_vector_type(4)));
typedef unsigned short us8 __attribute__((ext_vector_type(8)));

static __device__ __forceinline__ unsigned short f2b(float f) {
  __hip_bfloat16 h = __float2bfloat16(f);
  return __builtin_bit_cast(unsigned short, h);
}
static __device__ __forceinline__ float b2f(unsigned short u) {
  __hip_bfloat16 h = __builtin_bit_cast(__hip_bfloat16, u);
  return __bfloat162float(h);
}

// ---------------------------------------------------------------- convert
__global__ __launch_bounds__(256) void cvt_bf16(
    const float* __restrict__ in, unsigned short* __restrict__ out, int n8) {
  int i = blockIdx.x * 256 + threadIdx.x;
  if (i >= n8) return;
  const float4* p = reinterpret_cast<const float4*>(in) + (size_t)i * 2;
  float4 a = p[0], b = p[1];
  us8 v;
  v[0] = f2b(a.x); v[1] = f2b(a.y); v[2] = f2b(a.z); v[3] = f2b(a.w);
  v[4] = f2b(b.x); v[5] = f2b(b.y); v[6] = f2b(b.z); v[7] = f2b(b.w);
  reinterpret_cast<us8*>(out)[i] = v;
}

// ---------------------------------------------------------------- GEMM (B^T)
// C[m][n] = sum_k A[m][k] * Bw[n][k]   (both row-major along K, bf16)
// 128x128 tile, BK=32, 256 threads = 4 waves (2x2), each wave 64x64 (4x4 frags).
// MODE 0: bf16 out, no bias.  MODE 1: fp32 out + bias.
template <int MODE>
__global__ __launch_bounds__(256) void gemm_bt(
    const unsigned short* __restrict__ A, const unsigned short* __restrict__ Bw,
    const float* __restrict__ bias, void* __restrict__ Cout,
    int M, int Nn, int K) {
  __shared__ unsigned short a_sh[128 * 32];
  __shared__ unsigned short b_sh[128 * 32];
  const int tid = threadIdx.x;
  const int lane = tid & 63;
  const int w = tid >> 6;
  const int wr = w >> 1, wc = w & 1;
  const int l15 = lane & 15, l4 = lane >> 4;
  const int m0 = blockIdx.y * 128;
  const int n0 = blockIdx.x * 128;
  const int srow = tid >> 2;  // 0..63
  const int sc = tid & 3;     // 16B chunk within 64B row

  f32x4 acc[4][4] = {};

  for (int k0 = 0; k0 < K; k0 += 32) {
#pragma unroll
    for (int p = 0; p < 2; ++p) {
      int row = srow + p * 64;
      int swz = (sc ^ ((row >> 1) & 3)) * 8;  // chunk XOR-swizzle (2-way max on reads)
      *reinterpret_cast<bf16x8*>(&a_sh[row * 32 + swz]) =
          *reinterpret_cast<const bf16x8*>(&A[(size_t)(m0 + row) * K + k0 + sc * 8]);
      *reinterpret_cast<bf16x8*>(&b_sh[row * 32 + swz]) =
          *reinterpret_cast<const bf16x8*>(&Bw[(size_t)(n0 + row) * K + k0 + sc * 8]);
    }
    __syncthreads();
    bf16x8 af[4], bfr[4];
#pragma unroll
    for (int mf = 0; mf < 4; ++mf) {
      int r = wr * 64 + mf * 16 + l15;
      af[mf] = *reinterpret_cast<const bf16x8*>(&a_sh[r * 32 + (l4 ^ ((r >> 1) & 3)) * 8]);
    }
#pragma unroll
    for (int nf = 0; nf < 4; ++nf) {
      int r = wc * 64 + nf * 16 + l15;
      bfr[nf] = *reinterpret_cast<const bf16x8*>(&b_sh[r * 32 + (l4 ^ ((r >> 1) & 3)) * 8]);
    }
#pragma unroll
    for (int mf = 0; mf < 4; ++mf)
#pragma unroll
      for (int nf = 0; nf < 4; ++nf)
        acc[mf][nf] = __builtin_amdgcn_mfma_f32_16x16x32_bf16(af[mf], bfr[nf], acc[mf][nf], 0, 0, 0);
    __syncthreads();
  }
  // epilogue; C/D layout: col = lane&15, row = 4*(lane>>4)+j
#pragma unroll
  for (int mf = 0; mf < 4; ++mf)
#pragma unroll
    for (int nf = 0; nf < 4; ++nf) {
      int col = n0 + wc * 64 + nf * 16 + l15;
#pragma unroll
      for (int j = 0; j < 4; ++j) {
        int row = m0 + wr * 64 + mf * 16 + l4 * 4 + j;
        float v = acc[mf][nf][j];
        if (MODE == 1) {
          v += bias[col];
          reinterpret_cast<float*>(Cout)[(size_t)row * Nn + col] = v;
        } else {
          reinterpret_cast<unsigned short*>(Cout)[(size_t)row * Nn + col] = f2b(v);
        }
      }
    }
}

// ---------------------------------------------------------------- LN + RoPE
// One wave per (b, n, three in {0,1}, h) row; lane = d (0..63).
__global__ __launch_bounds__(256) void ln_rope(
    const unsigned short* __restrict__ qkv,  // [4096][3072] bf16
    const float* __restrict__ fcos, const float* __restrict__ fsin,  // [2048][64]
    unsigned short* __restrict__ qo, unsigned short* __restrict__ ko)  // [B*H][2048][64]
{
  const int rid = blockIdx.x * 4 + (threadIdx.x >> 6);
  const int lane = threadIdx.x & 63;
  const int h = rid & 15;
  const int three = (rid >> 4) & 1;
  const int n = (rid >> 5) & 2047;
  const int b = rid >> 16;
  const int m = b * 2048 + n;
  float v = b2f(qkv[(size_t)m * 3072 + three * 1024 + h * 64 + lane]);
  float s = v, s2 = v * v;
#pragma unroll
  for (int off = 32; off; off >>= 1) {
    s += __shfl_xor(s, off);
    s2 += __shfl_xor(s2, off);
  }
  float mu = s * (1.f / 64.f);
  float var = s2 * (1.f / 64.f) - mu * mu;
  float inv = rsqrtf(var + 1e-6f);
  float t = (v - mu) * inv;
  float other = __shfl_xor(t, 32);  // rotate-half partner
  float c = fcos[n * 64 + lane], sn = fsin[n * 64 + lane];
  float r = (lane < 32) ? (t * c - other * sn) : (t * c + other * sn);
  unsigned short* dst = three ? ko : qo;
  dst[((size_t)(b * 16 + h) * 2048 + n) * 64 + lane] = f2b(r);
}

// ---------------------------------------------------------------- V transpose
// v [b,h,n,d] (from qkv three=2) -> vt [b,h,d,n]
__global__ __launch_bounds__(256) void v_transpose(
    const unsigned short* __restrict__ qkv, unsigned short* __restrict__ vt) {
  __shared__ unsigned short sh[64][72];  // +8 pad keeps 16B alignment
  const int tid = threadIdx.x;
  const int bid = blockIdx.x;
  const int nt = bid & 31;
  const int h = (bid >> 5) & 15;
  const int b = bid >> 9;
  // stage: 64 rows x 8 chunks = 512 items -> 2 passes of 256 threads
#pragma unroll
  for (int p = 0; p < 2; ++p) {
    int g = p * 256 + tid;
    int i = g >> 3, c = g & 7;
    us8 v = *reinterpret_cast<const us8*>(
        &qkv[(size_t)(b * 2048 + nt * 64 + i) * 3072 + 2048 + h * 64 + c * 8]);
    *reinterpret_cast<us8*>(&sh[i][c * 8]) = v;
  }
  __syncthreads();
  const int bh = b * 16 + h;
#pragma unroll
  for (int p = 0; p < 2; ++p) {
    int g = p * 256 + tid;
    int d = g >> 3, c2 = g & 7;
    us8 v;
#pragma unroll
    for (int j = 0; j < 8; ++j) v[j] = sh[c2 * 8 + j][d];
    *reinterpret_cast<us8*>(&vt[((size_t)bh * 64 + d) * 2048 + nt * 64 + c2 * 8]) = v;
  }
}

// ---------------------------------------------------------------- attention
// 1 block = one (b,h) and a 64-row Q tile. 4 waves x 16 Q rows. KV tiles of 64.
__global__ __launch_bounds__(256) void attn_kern(
    const unsigned short* __restrict__ Q,   // [B*H][2048][64]
    const unsigned short* __restrict__ Kk,  // [B*H][2048][64]
    const unsigned short* __restrict__ Vt,  // [B*H][64][2048]
    unsigned short* __restrict__ O)         // [B][2048][1024] (col = h*64+d)
{
  __shared__ unsigned short k_sh[64 * 64];
  __shared__ unsigned short v_sh[64 * 64];
  __shared__ unsigned short p_sh[4][16][72];
  const int tid = threadIdx.x;
  const int lane = tid & 63;
  const int w = tid >> 6;
  const int l15 = lane & 15, l4 = lane >> 4;
  const int bid = blockIdx.x;
  const int qt = bid & 31;
  const int bh = bid >> 5;
  const int h = bh & 15, b = bh >> 4;
  const unsigned short* qb = Q + (size_t)bh * 2048 * 64;
  const unsigned short* kb = Kk + (size_t)bh * 2048 * 64;
  const unsigned short* vb = Vt + (size_t)bh * 64 * 2048;
  const int q0 = qt * 64 + w * 16;

  bf16x8 aq[2];
#pragma unroll
  for (int ks = 0; ks < 2; ++ks)
    aq[ks] = *reinterpret_cast<const bf16x8*>(&qb[(size_t)(q0 + l15) * 64 + ks * 32 + l4 * 8]);

  f32x4 acc[4] = {};
  float mrow[4], lrow[4];
#pragma unroll
  for (int j = 0; j < 4; ++j) { mrow[j] = -1e30f; lrow[j] = 0.f; }

  for (int kt = 0; kt < 32; ++kt) {
    // stage K tile [kv][d] and V^T tile [d][kv], XOR-swizzled 16B chunks
#pragma unroll
    for (int p = 0; p < 2; ++p) {
      int g = p * 256 + tid;
      int row = g >> 3, c = g & 7;
      int swz = (c ^ (row & 7)) * 8;
      *reinterpret_cast<bf16x8*>(&k_sh[row * 64 + swz]) =
          *reinterpret_cast<const bf16x8*>(&kb[(size_t)(kt * 64 + row) * 64 + c * 8]);
      *reinterpret_cast<bf16x8*>(&v_sh[row * 64 + swz]) =
          *reinterpret_cast<const bf16x8*>(&vb[(size_t)row * 2048 + kt * 64 + c * 8]);
    }
    __syncthreads();
    // S = (Q K^T) * scale : 4 col-frags x (K=64 in 2 mfma steps)
    f32x4 s[4];
#pragma unroll
    for (int nf = 0; nf < 4; ++nf) {
      f32x4 z = {0.f, 0.f, 0.f, 0.f};
      int r = nf * 16 + l15;
#pragma unroll
      for (int ks = 0; ks < 2; ++ks) {
        int c = ks * 4 + l4;
        bf16x8 bk = *reinterpret_cast<const bf16x8*>(&k_sh[r * 64 + (c ^ (r & 7)) * 8]);
        z = __builtin_amdgcn_mfma_f32_16x16x32_bf16(aq[ks], bk, z, 0, 0, 0);
      }
      s[nf] = z * 0.125f;  // D^-0.5
    }
    // online softmax; row j of 16-lane group: reduce over lane bits 0..3
    float corr[4];
#pragma unroll
    for (int j = 0; j < 4; ++j) {
      float mx = fmaxf(fmaxf(s[0][j], s[1][j]), fmaxf(s[2][j], s[3][j]));
      mx = fmaxf(mx, __shfl_xor(mx, 1));
      mx = fmaxf(mx, __shfl_xor(mx, 2));
      mx = fmaxf(mx, __shfl_xor(mx, 4));
      mx = fmaxf(mx, __shfl_xor(mx, 8));
      float mn = fmaxf(mrow[j], mx);
      corr[j] = __expf(mrow[j] - mn);
      mrow[j] = mn;
    }
    float rs[4] = {0.f, 0.f, 0.f, 0.f};
#pragma unroll
    for (int nf = 0; nf < 4; ++nf)
#pragma unroll
      for (int j = 0; j < 4; ++j) {
        float pv = __expf(s[nf][j] - mrow[j]);
        s[nf][j] = pv;
        rs[j] += pv;
      }
#pragma unroll
    for (int j = 0; j < 4; ++j) {
      float t = rs[j];
      t += __shfl_xor(t, 1);
      t += __shfl_xor(t, 2);
      t += __shfl_xor(t, 4);
      t += __shfl_xor(t, 8);
      lrow[j] = lrow[j] * corr[j] + t;
#pragma unroll
      for (int nf = 0; nf < 4; ++nf) acc[nf][j] *= corr[j];
    }
    // P -> LDS (bf16), re-shaped into A-fragment layout
#pragma unroll
    for (int nf = 0; nf < 4; ++nf)
#pragma unroll
      for (int j = 0; j < 4; ++j)
        p_sh[w][l4 * 4 + j][nf * 16 + l15] = f2b(s[nf][j]);
    __syncthreads();
    // O += P V : A-frags from p_sh, B-frags from v_sh (V^T layout)
    bf16x8 ap[2];
#pragma unroll
    for (int ks = 0; ks < 2; ++ks)
      ap[ks] = *reinterpret_cast<const bf16x8*>(&p_sh[w][l15][ks * 32 + l4 * 8]);
#pragma unroll
    for (int nf = 0; nf < 4; ++nf) {
      int r = nf * 16 + l15;
#pragma unroll
      for (int ks = 0; ks < 2; ++ks) {
        int c = ks * 4 + l4;
        bf16x8 bv = *reinterpret_cast<const bf16x8*>(&v_sh[r * 64 + (c ^ (r & 7)) * 8]);
        acc[nf] = __builtin_amdgcn_mfma_f32_16x16x32_bf16(ap[ks], bv, acc[nf], 0, 0, 0);
      }
    }
    __syncthreads();
  }
  // epilogue: O[b, q0+r, h*64+d] = acc / l
#pragma unroll
  for (int nf = 0; nf < 4; ++nf)
#pragma unroll
    for (int j = 0; j < 4; ++j) {
      int row = q0 + l4 * 4 + j;
      int d = nf * 16 + l15;
      O[((size_t)b * 2048 + row) * 1024 + h * 64 + d] = f2b(acc[nf][j] / lrow[j]);
    }
}

// ---------------------------------------------------------------- launch
extern "C" void kernel_launch(void* const* d_in, const int* in_sizes, int n_in,
                              void* d_out, int out_size, void* d_ws, size_t ws_size,
                              hipStream_t stream) {
  (void)in_sizes; (void)n_in; (void)out_size; (void)ws_size;
  const float* x      = (const float*)d_in[0];
  const float* w_qkv  = (const float*)d_in[1];
  const float* w_proj = (const float*)d_in[2];
  const float* b_proj = (const float*)d_in[3];
  const float* fcos   = (const float*)d_in[4];
  const float* fsin   = (const float*)d_in[5];
  float* out = (float*)d_out;
  char* ws = (char*)d_ws;

  unsigned short* x_bf     = (unsigned short*)(ws + 0);         // 8 MB
  unsigned short* wqkv_bf  = (unsigned short*)(ws + 8388608);   // 6 MB
  unsigned short* wproj_bf = (unsigned short*)(ws + 14680064);  // 2 MB
  unsigned short* qkv_bf   = (unsigned short*)(ws + 16777216);  // 24 MB
  unsigned short* q_bf     = (unsigned short*)(ws + 41943040);  // 8 MB
  unsigned short* k_bf     = (unsigned short*)(ws + 50331648);  // 8 MB
  unsigned short* vt_bf    = (unsigned short*)(ws + 58720256);  // 8 MB
  unsigned short* ao_bf    = (unsigned short*)(ws + 67108864);  // 8 MB  (total 72 MB)

  cvt_bf16<<<2048, 256, 0, stream>>>(x, x_bf, 4096 * 1024 / 8);
  cvt_bf16<<<1536, 256, 0, stream>>>(w_qkv, wqkv_bf, 3072 * 1024 / 8);
  cvt_bf16<<<512, 256, 0, stream>>>(w_proj, wproj_bf, 1024 * 1024 / 8);
  gemm_bt<0><<<dim3(24, 32), 256, 0, stream>>>(x_bf, wqkv_bf, nullptr, qkv_bf, 4096, 3072, 1024);
  ln_rope<<<32768, 256, 0, stream>>>(qkv_bf, fcos, fsin, q_bf, k_bf);
  v_transpose<<<1024, 256, 0, stream>>>(qkv_bf, vt_bf);
  attn_kern<<<1024, 256, 0, stream>>>(q_bf, k_bf, vt_bf, ao_bf);
  gemm_bt<1><<<dim3(8, 32), 256, 0, stream>>>(ao_bf, wproj_bf, b_proj, out, 4096, 1024, 1024);
}